// Round 1
// baseline (112.560 us; speedup 1.0000x reference)
//
#include <hip/hip_runtime.h>
#include <math.h>

#define N0 2048
#define N1 1024
#define M0T 32                     // 2048 / 64-row tiles
#define M1T 32                     // 1024 / 32-row tiles
#define NB0 (M0T * (M0T + 1) / 2)  // 528 lower-tri tile pairs, layer 0
#define NB1 (M1T * (M1T + 1) / 2)  // 528 lower-tri tile pairs, layer 1
#define NBLK0 (2 * NB0)            // 1056 blocks (each tile pair j-split in 2)
#define NBLK1 (2 * NB1)            // 1056 blocks
#define NBTOT (NBLK0 + NBLK1)      // 2112

// ws layout (floats): kn0[N0*9] inv0[N0*9] kn1[N1*25] inv1[N1*25]
// then (16B-aligned): double acc[2], unsigned cnt

// ---------------------------------------------------------------------------
// prep: normalize + invert (+1 Newton polish), all fp32, reg-resident.
// Also zeroes the accumulator/counter used by pairs' fused finalize —
// prep completes before pairs starts (stream order), so this is replay-safe
// regardless of workspace initial contents.
// ---------------------------------------------------------------------------
__global__ __launch_bounds__(64) void prep_kernel(const float* __restrict__ k0,
                                                  const float* __restrict__ k1,
                                                  float* __restrict__ kn0,
                                                  float* __restrict__ inv0,
                                                  float* __restrict__ kn1,
                                                  float* __restrict__ inv1,
                                                  double* __restrict__ acc,
                                                  unsigned* __restrict__ cnt) {
    int t = blockIdx.x * blockDim.x + threadIdx.x;
    if (t == 0) { acc[0] = 0.0; acc[1] = 0.0; *cnt = 0u; }
    if (t < N0) {
        // ---- 3x3: normalize + adjugate inverse + Newton ----
        float a[9];
        float ss = 0.0f;
#pragma unroll
        for (int e = 0; e < 9; ++e) { a[e] = k0[t * 9 + e]; ss = fmaf(a[e], a[e], ss); }
        float rn = 1.0f / (sqrtf(ss) + 1e-8f);
#pragma unroll
        for (int e = 0; e < 9; ++e) a[e] *= rn;
        float c00 = a[4] * a[8] - a[5] * a[7];
        float c01 = -(a[3] * a[8] - a[5] * a[6]);
        float c02 = a[3] * a[7] - a[4] * a[6];
        float det = a[0] * c00 + a[1] * c01 + a[2] * c02;
        float id = 1.0f / det;
        float x[9];
        x[0] = c00 * id;
        x[1] = (a[2] * a[7] - a[1] * a[8]) * id;
        x[2] = (a[1] * a[5] - a[2] * a[4]) * id;
        x[3] = c01 * id;
        x[4] = (a[0] * a[8] - a[2] * a[6]) * id;
        x[5] = (a[2] * a[3] - a[0] * a[5]) * id;
        x[6] = c02 * id;
        x[7] = (a[1] * a[6] - a[0] * a[7]) * id;
        x[8] = (a[0] * a[4] - a[1] * a[3]) * id;
        // Newton polish: x <- x(2I - a x)
        float r[9];
#pragma unroll
        for (int i = 0; i < 3; ++i)
#pragma unroll
            for (int j = 0; j < 3; ++j) {
                float m = a[i * 3 + 0] * x[0 * 3 + j];
                m = fmaf(a[i * 3 + 1], x[1 * 3 + j], m);
                m = fmaf(a[i * 3 + 2], x[2 * 3 + j], m);
                r[i * 3 + j] = ((i == j) ? 2.0f : 0.0f) - m;
            }
        float xn[9];
#pragma unroll
        for (int i = 0; i < 3; ++i)
#pragma unroll
            for (int j = 0; j < 3; ++j) {
                float m = x[i * 3 + 0] * r[0 * 3 + j];
                m = fmaf(x[i * 3 + 1], r[1 * 3 + j], m);
                m = fmaf(x[i * 3 + 2], r[2 * 3 + j], m);
                xn[i * 3 + j] = m;
            }
#pragma unroll
        for (int e = 0; e < 9; ++e) {
            kn0[t * 9 + e] = a[e];
            inv0[t * 9 + e] = xn[e];
        }
    } else {
        int u = t - N0;
        if (u < N1) {
            // ---- 5x5: normalize + branchless GJ w/ partial pivot + Newton ----
            float A[5][5], B[5][5], K[5][5];
            float ss = 0.0f;
#pragma unroll
            for (int r = 0; r < 5; ++r)
#pragma unroll
                for (int c = 0; c < 5; ++c) {
                    float v = k1[u * 25 + r * 5 + c];
                    A[r][c] = v;
                    ss = fmaf(v, v, ss);
                }
            float rn = 1.0f / (sqrtf(ss) + 1e-8f);
#pragma unroll
            for (int r = 0; r < 5; ++r)
#pragma unroll
                for (int c = 0; c < 5; ++c) {
                    A[r][c] *= rn;
                    K[r][c] = A[r][c];
                    kn1[u * 25 + r * 5 + c] = A[r][c];
                    B[r][c] = (r == c) ? 1.0f : 0.0f;
                }
#pragma unroll
            for (int k = 0; k < 5; ++k) {
#pragma unroll
                for (int r = k + 1; r < 5; ++r) {
                    bool sw = fabsf(A[r][k]) > fabsf(A[k][k]);
#pragma unroll
                    for (int c = k; c < 5; ++c) {
                        float Ar = A[r][c], Ak = A[k][c];
                        A[r][c] = sw ? Ak : Ar;
                        A[k][c] = sw ? Ar : Ak;
                    }
#pragma unroll
                    for (int c = 0; c < 5; ++c) {
                        float Br = B[r][c], Bk = B[k][c];
                        B[r][c] = sw ? Bk : Br;
                        B[k][c] = sw ? Br : Bk;
                    }
                }
                float piv = 1.0f / A[k][k];
#pragma unroll
                for (int c = k; c < 5; ++c) A[k][c] *= piv;
#pragma unroll
                for (int c = 0; c < 5; ++c) B[k][c] *= piv;
#pragma unroll
                for (int r = 0; r < 5; ++r) {
                    if (r == k) continue;
                    float f = A[r][k];
#pragma unroll
                    for (int c = k; c < 5; ++c) A[r][c] = fmaf(-f, A[k][c], A[r][c]);
#pragma unroll
                    for (int c = 0; c < 5; ++c) B[r][c] = fmaf(-f, B[k][c], B[r][c]);
                }
            }
            // Newton polish: B <- B(2I - K B)
            float R[5][5];
#pragma unroll
            for (int i = 0; i < 5; ++i)
#pragma unroll
                for (int j = 0; j < 5; ++j) {
                    float m = K[i][0] * B[0][j];
#pragma unroll
                    for (int k = 1; k < 5; ++k) m = fmaf(K[i][k], B[k][j], m);
                    R[i][j] = ((i == j) ? 2.0f : 0.0f) - m;
                }
#pragma unroll
            for (int i = 0; i < 5; ++i)
#pragma unroll
                for (int j = 0; j < 5; ++j) {
                    float m = B[i][0] * R[0][j];
#pragma unroll
                    for (int k = 1; k < 5; ++k) m = fmaf(B[i][k], R[k][j], m);
                    inv1[u * 25 + i * 5 + j] = m;
                }
        }
    }
}

__device__ __forceinline__ void tri_decode(int t, int& bi, int& bj) {
    int b = (int)((sqrtf(8.0f * t + 1.0f) - 1.0f) * 0.5f);
    while ((b + 1) * (b + 2) / 2 <= t) ++b;
    while (b * (b + 1) / 2 > t) --b;
    bi = b;
    bj = t - b * (b + 1) / 2;
}

// ---------------------------------------------------------------------------
// Fused pair-distance + finalize kernel, j-split triangular grid.
//   blocks [0, NBLK0):      layer 0 (d=3): 64x32 half-tile, 4x2 pairs/thread
//   blocks [NBLK0, NBTOT):  layer 1 (d=5): 32x16 half-tile, 2x1 pairs/thread
// Finer blocks halve the dispatch-tail quantum (1056 -> 2112 blocks).
// Last-done block (atomic counter) writes the final scalar -> no 3rd launch.
// Bank-conflict audit (32 banks, broadcast across the 4 ti-groups/wave):
//   L0 a: stride 36f -> banks {+0,+4,+8,+12}   distinct
//   L0 b: stride 18f -> 16 tj all-distinct banks
//   L1 a: stride 50f -> banks {+0,+18,+4,+22}  distinct
//   L1 b: stride 25f -> 16 tj all-distinct banks
// ---------------------------------------------------------------------------
__global__ __launch_bounds__(256) void pairs_kernel(const float* __restrict__ inv0,
                                                    const float* __restrict__ kn0,
                                                    const float* __restrict__ inv1,
                                                    const float* __restrict__ kn1,
                                                    double* __restrict__ acc,
                                                    unsigned* __restrict__ cnt,
                                                    float* __restrict__ out) {
    __shared__ __align__(16) float sA[800];  // L0: 64*9=576, L1: 32*25=800
    __shared__ __align__(16) float sB[400];  // L0: 32*9=288, L1: 16*25=400
    int tid = threadIdx.x;
    float contrib = 0.0f;

    if (blockIdx.x < NBLK0) {
        // ---------------- layer 0: d=3 ----------------
        int t = blockIdx.x;
        int pb = t >> 1, h = t & 1;
        int bi, bj;
        tri_decode(pb, bi, bj);

        const float4* gA = (const float4*)(inv0 + bi * 576);           // 144 f4
        const float4* gB = (const float4*)(kn0 + bj * 576 + h * 288);  // 72 f4
        if (tid < 216) {
            if (tid < 144) ((float4*)sA)[tid] = gA[tid];
            else ((float4*)sB)[tid - 144] = gB[tid - 144];
        }
        __syncthreads();

        int ti = tid >> 4, tj = tid & 15;
        int ibase = bi * 64 + ti * 4;
        int jbase = bj * 64 + h * 32 + tj * 2;
        float a[4][9];
#pragma unroll
        for (int u = 0; u < 4; ++u)
#pragma unroll
            for (int e = 0; e < 9; ++e) a[u][e] = sA[(ti * 4 + u) * 9 + e];
#pragma unroll
        for (int v = 0; v < 2; ++v) {
            float b[9];
#pragma unroll
            for (int e = 0; e < 9; ++e) b[e] = sB[(tj * 2 + v) * 9 + e];
#pragma unroll
            for (int u = 0; u < 4; ++u) {
                float s = 0.0f;
#pragma unroll
                for (int r = 0; r < 3; ++r)
#pragma unroll
                    for (int c = 0; c < 3; ++c) {
                        float m = a[u][r * 3 + 0] * b[c];
                        m = fmaf(a[u][r * 3 + 1], b[3 + c], m);
                        m = fmaf(a[u][r * 3 + 2], b[6 + c], m);
                        float d = ((r == c) ? 1.0f : 0.0f) - m;
                        s = fmaf(d, d, s);
                    }
                bool take = ((ibase + u) > (jbase + v)) && (s < 1.0f);
                contrib += take ? (1.0f - __builtin_amdgcn_sqrtf(s)) : 0.0f;
            }
        }
    } else {
        // ---------------- layer 1: d=5 ----------------
        int t = blockIdx.x - NBLK0;
        int pb = t >> 1, h = t & 1;
        int bi, bj;
        tri_decode(pb, bi, bj);

        const float4* gA = (const float4*)(inv1 + bi * 800);                 // 200 f4
        const float4* gB = (const float4*)(kn1 + (bj * 32 + h * 16) * 25);   // 100 f4
        for (int e = tid; e < 300; e += 256) {
            if (e < 200) ((float4*)sA)[e] = gA[e];
            else ((float4*)sB)[e - 200] = gB[e - 200];
        }
        __syncthreads();

        int ti = tid >> 4, tj = tid & 15;  // ti: 2 rows each (32), tj: 1 col (16)
        int ibase = bi * 32 + ti * 2;
        int j = bj * 32 + h * 16 + tj;
        float a[2][25];
#pragma unroll
        for (int u = 0; u < 2; ++u)
#pragma unroll
            for (int e = 0; e < 25; ++e) a[u][e] = sA[(ti * 2 + u) * 25 + e];
        float b[25];
#pragma unroll
        for (int e = 0; e < 25; ++e) b[e] = sB[tj * 25 + e];
#pragma unroll
        for (int u = 0; u < 2; ++u) {
            float s = 0.0f;
#pragma unroll
            for (int r = 0; r < 5; ++r)
#pragma unroll
                for (int c = 0; c < 5; ++c) {
                    float m = a[u][r * 5 + 0] * b[c];
#pragma unroll
                    for (int k = 1; k < 5; ++k) m = fmaf(a[u][r * 5 + k], b[k * 5 + c], m);
                    float d = ((r == c) ? 1.0f : 0.0f) - m;
                    s = fmaf(d, d, s);
                }
            bool take = ((ibase + u) > j) && (s < 1.0f);
            contrib += take ? (1.0f - __builtin_amdgcn_sqrtf(s)) : 0.0f;
        }
    }

    // block reduction
#pragma unroll
    for (int off = 32; off; off >>= 1) contrib += __shfl_down(contrib, off);
    __shared__ float wsum[4];
    if ((tid & 63) == 0) wsum[tid >> 6] = contrib;
    __syncthreads();

    // fused finalize: device-scope atomics; last-done block writes the result
    if (tid == 0) {
        float bs = wsum[0] + wsum[1] + wsum[2] + wsum[3];
        int layer = (blockIdx.x < NBLK0) ? 0 : 1;
        atomicAdd(&acc[layer], (double)bs);
        __threadfence();
        unsigned old = atomicAdd(cnt, 1u);
        if (old == NBTOT - 1) {
            __threadfence();
            double S0 = atomicAdd(&acc[0], 0.0);  // coherent read at L2
            double S1 = atomicAdd(&acc[1], 0.0);
            // final = (2*S0/(n0(n0-1)) + 2*S1/(n1(n1-1))) / 2
            double res = S0 / ((double)N0 * (double)(N0 - 1)) +
                         S1 / ((double)N1 * (double)(N1 - 1));
            out[0] = (float)res;
        }
    }
}

extern "C" void kernel_launch(void* const* d_in, const int* in_sizes, int n_in,
                              void* d_out, int out_size, void* d_ws, size_t ws_size,
                              hipStream_t stream) {
    const float* k0 = (const float*)d_in[0];  // (2048,3,3)
    const float* k1 = (const float*)d_in[1];  // (1024,5,5)
    float* out = (float*)d_out;

    float* ws = (float*)d_ws;
    float* kn0 = ws;                  // 18432 floats
    float* inv0 = kn0 + N0 * 9;       // 18432
    float* kn1 = inv0 + N0 * 9;       // 25600
    float* inv1 = kn1 + N1 * 25;      // 25600
    // 88064 floats = 352256 B (16B-aligned) -> accumulators
    double* acc = (double*)(inv1 + N1 * 25);
    unsigned* cnt = (unsigned*)(acc + 2);

    int totalPrep = N0 + N1;  // 3072 threads, block=64 -> 48 blocks
    prep_kernel<<<(totalPrep + 63) / 64, 64, 0, stream>>>(k0, k1, kn0, inv0, kn1, inv1,
                                                          acc, cnt);
    pairs_kernel<<<NBTOT, 256, 0, stream>>>(inv0, kn0, inv1, kn1, acc, cnt, out);
}

// Round 2
// 69.821 us; speedup vs baseline: 1.6121x; 1.6121x over previous
//
#include <hip/hip_runtime.h>
#include <math.h>

#define N0 2048
#define N1 1024
#define M0T 32                     // 2048 / 64-row tiles
#define M1T 32                     // 1024 / 32-row tiles
#define NB0 (M0T * (M0T + 1) / 2)  // 528 lower-tri tile pairs, layer 0
#define NB1 (M1T * (M1T + 1) / 2)  // 528 lower-tri tile pairs, layer 1
#define NBLK0 (2 * NB0)            // 1056 blocks (each tile pair j-split in 2)
#define NBLK1 (2 * NB1)            // 1056 blocks
#define NBTOT (NBLK0 + NBLK1)      // 2112

// ws layout (floats): kn0[N0*9] inv0[N0*9] kn1[N1*25] inv1[N1*25] partial[NBTOT]
//
// R1 lesson (counters): fused last-block finalize via same-address device atomics
// serialized 2112 blocks at the coherence point (~25ns each = ~53us queue;
// Occupancy 24% == 1 straggler wave per block). Finalize is a separate kernel
// again — distinct-address stores, kernel-boundary coherence, no fences.

// ---------------------------------------------------------------------------
// prep: normalize + invert (+1 Newton polish), all fp32, reg-resident.
// ---------------------------------------------------------------------------
__global__ __launch_bounds__(64) void prep_kernel(const float* __restrict__ k0,
                                                  const float* __restrict__ k1,
                                                  float* __restrict__ kn0,
                                                  float* __restrict__ inv0,
                                                  float* __restrict__ kn1,
                                                  float* __restrict__ inv1) {
    int t = blockIdx.x * blockDim.x + threadIdx.x;
    if (t < N0) {
        // ---- 3x3: normalize + adjugate inverse + Newton ----
        float a[9];
        float ss = 0.0f;
#pragma unroll
        for (int e = 0; e < 9; ++e) { a[e] = k0[t * 9 + e]; ss = fmaf(a[e], a[e], ss); }
        float rn = 1.0f / (sqrtf(ss) + 1e-8f);
#pragma unroll
        for (int e = 0; e < 9; ++e) a[e] *= rn;
        float c00 = a[4] * a[8] - a[5] * a[7];
        float c01 = -(a[3] * a[8] - a[5] * a[6]);
        float c02 = a[3] * a[7] - a[4] * a[6];
        float det = a[0] * c00 + a[1] * c01 + a[2] * c02;
        float id = 1.0f / det;
        float x[9];
        x[0] = c00 * id;
        x[1] = (a[2] * a[7] - a[1] * a[8]) * id;
        x[2] = (a[1] * a[5] - a[2] * a[4]) * id;
        x[3] = c01 * id;
        x[4] = (a[0] * a[8] - a[2] * a[6]) * id;
        x[5] = (a[2] * a[3] - a[0] * a[5]) * id;
        x[6] = c02 * id;
        x[7] = (a[1] * a[6] - a[0] * a[7]) * id;
        x[8] = (a[0] * a[4] - a[1] * a[3]) * id;
        // Newton polish: x <- x(2I - a x)
        float r[9];
#pragma unroll
        for (int i = 0; i < 3; ++i)
#pragma unroll
            for (int j = 0; j < 3; ++j) {
                float m = a[i * 3 + 0] * x[0 * 3 + j];
                m = fmaf(a[i * 3 + 1], x[1 * 3 + j], m);
                m = fmaf(a[i * 3 + 2], x[2 * 3 + j], m);
                r[i * 3 + j] = ((i == j) ? 2.0f : 0.0f) - m;
            }
        float xn[9];
#pragma unroll
        for (int i = 0; i < 3; ++i)
#pragma unroll
            for (int j = 0; j < 3; ++j) {
                float m = x[i * 3 + 0] * r[0 * 3 + j];
                m = fmaf(x[i * 3 + 1], r[1 * 3 + j], m);
                m = fmaf(x[i * 3 + 2], r[2 * 3 + j], m);
                xn[i * 3 + j] = m;
            }
#pragma unroll
        for (int e = 0; e < 9; ++e) {
            kn0[t * 9 + e] = a[e];
            inv0[t * 9 + e] = xn[e];
        }
    } else {
        int u = t - N0;
        if (u < N1) {
            // ---- 5x5: normalize + branchless GJ w/ partial pivot + Newton ----
            float A[5][5], B[5][5], K[5][5];
            float ss = 0.0f;
#pragma unroll
            for (int r = 0; r < 5; ++r)
#pragma unroll
                for (int c = 0; c < 5; ++c) {
                    float v = k1[u * 25 + r * 5 + c];
                    A[r][c] = v;
                    ss = fmaf(v, v, ss);
                }
            float rn = 1.0f / (sqrtf(ss) + 1e-8f);
#pragma unroll
            for (int r = 0; r < 5; ++r)
#pragma unroll
                for (int c = 0; c < 5; ++c) {
                    A[r][c] *= rn;
                    K[r][c] = A[r][c];
                    kn1[u * 25 + r * 5 + c] = A[r][c];
                    B[r][c] = (r == c) ? 1.0f : 0.0f;
                }
#pragma unroll
            for (int k = 0; k < 5; ++k) {
#pragma unroll
                for (int r = k + 1; r < 5; ++r) {
                    bool sw = fabsf(A[r][k]) > fabsf(A[k][k]);
#pragma unroll
                    for (int c = k; c < 5; ++c) {
                        float Ar = A[r][c], Ak = A[k][c];
                        A[r][c] = sw ? Ak : Ar;
                        A[k][c] = sw ? Ar : Ak;
                    }
#pragma unroll
                    for (int c = 0; c < 5; ++c) {
                        float Br = B[r][c], Bk = B[k][c];
                        B[r][c] = sw ? Bk : Br;
                        B[k][c] = sw ? Br : Bk;
                    }
                }
                float piv = 1.0f / A[k][k];
#pragma unroll
                for (int c = k; c < 5; ++c) A[k][c] *= piv;
#pragma unroll
                for (int c = 0; c < 5; ++c) B[k][c] *= piv;
#pragma unroll
                for (int r = 0; r < 5; ++r) {
                    if (r == k) continue;
                    float f = A[r][k];
#pragma unroll
                    for (int c = k; c < 5; ++c) A[r][c] = fmaf(-f, A[k][c], A[r][c]);
#pragma unroll
                    for (int c = 0; c < 5; ++c) B[r][c] = fmaf(-f, B[k][c], B[r][c]);
                }
            }
            // Newton polish: B <- B(2I - K B)
            float R[5][5];
#pragma unroll
            for (int i = 0; i < 5; ++i)
#pragma unroll
                for (int j = 0; j < 5; ++j) {
                    float m = K[i][0] * B[0][j];
#pragma unroll
                    for (int k = 1; k < 5; ++k) m = fmaf(K[i][k], B[k][j], m);
                    R[i][j] = ((i == j) ? 2.0f : 0.0f) - m;
                }
#pragma unroll
            for (int i = 0; i < 5; ++i)
#pragma unroll
                for (int j = 0; j < 5; ++j) {
                    float m = B[i][0] * R[0][j];
#pragma unroll
                    for (int k = 1; k < 5; ++k) m = fmaf(B[i][k], R[k][j], m);
                    inv1[u * 25 + i * 5 + j] = m;
                }
        }
    }
}

__device__ __forceinline__ void tri_decode(int t, int& bi, int& bj) {
    int b = (int)((sqrtf(8.0f * t + 1.0f) - 1.0f) * 0.5f);
    while ((b + 1) * (b + 2) / 2 <= t) ++b;
    while (b * (b + 1) / 2 > t) --b;
    bi = b;
    bj = t - b * (b + 1) / 2;
}

// ---------------------------------------------------------------------------
// Pair-distance kernel, j-split triangular grid, plain per-block partial store.
//   blocks [0, NBLK0):      layer 0 (d=3): 64x32 half-tile, 4x2 pairs/thread
//   blocks [NBLK0, NBTOT):  layer 1 (d=5): 32x16 half-tile, 2x1 pairs/thread
// Bank-conflict audit (32 banks, broadcast within 16-lane tj groups):
//   L0 a: stride 36f -> banks {0,4,8,12}+e  distinct;  L0 b: stride 18f -> 16 distinct
//   L1 a: stride 50f -> banks {0,18,4,22}+e distinct;  L1 b: stride 25f -> 16 distinct
// (R1 counters: SQ_LDS_BANK_CONFLICT == 0 confirms.)
// ---------------------------------------------------------------------------
__global__ __launch_bounds__(256) void pairs_kernel(const float* __restrict__ inv0,
                                                    const float* __restrict__ kn0,
                                                    const float* __restrict__ inv1,
                                                    const float* __restrict__ kn1,
                                                    float* __restrict__ partial) {
    __shared__ __align__(16) float sA[800];  // L0: 64*9=576, L1: 32*25=800
    __shared__ __align__(16) float sB[400];  // L0: 32*9=288, L1: 16*25=400
    int tid = threadIdx.x;
    float contrib = 0.0f;

    if (blockIdx.x < NBLK0) {
        // ---------------- layer 0: d=3 ----------------
        int t = blockIdx.x;
        int pb = t >> 1, h = t & 1;
        int bi, bj;
        tri_decode(pb, bi, bj);

        const float4* gA = (const float4*)(inv0 + bi * 576);           // 144 f4
        const float4* gB = (const float4*)(kn0 + bj * 576 + h * 288);  // 72 f4
        if (tid < 216) {
            if (tid < 144) ((float4*)sA)[tid] = gA[tid];
            else ((float4*)sB)[tid - 144] = gB[tid - 144];
        }
        __syncthreads();

        int ti = tid >> 4, tj = tid & 15;
        int ibase = bi * 64 + ti * 4;
        int jbase = bj * 64 + h * 32 + tj * 2;
        float a[4][9];
#pragma unroll
        for (int u = 0; u < 4; ++u)
#pragma unroll
            for (int e = 0; e < 9; ++e) a[u][e] = sA[(ti * 4 + u) * 9 + e];
#pragma unroll
        for (int v = 0; v < 2; ++v) {
            float b[9];
#pragma unroll
            for (int e = 0; e < 9; ++e) b[e] = sB[(tj * 2 + v) * 9 + e];
#pragma unroll
            for (int u = 0; u < 4; ++u) {
                float s = 0.0f;
#pragma unroll
                for (int r = 0; r < 3; ++r)
#pragma unroll
                    for (int c = 0; c < 3; ++c) {
                        float m = a[u][r * 3 + 0] * b[c];
                        m = fmaf(a[u][r * 3 + 1], b[3 + c], m);
                        m = fmaf(a[u][r * 3 + 2], b[6 + c], m);
                        float d = ((r == c) ? 1.0f : 0.0f) - m;
                        s = fmaf(d, d, s);
                    }
                bool take = ((ibase + u) > (jbase + v)) && (s < 1.0f);
                contrib += take ? (1.0f - __builtin_amdgcn_sqrtf(s)) : 0.0f;
            }
        }
    } else {
        // ---------------- layer 1: d=5 ----------------
        int t = blockIdx.x - NBLK0;
        int pb = t >> 1, h = t & 1;
        int bi, bj;
        tri_decode(pb, bi, bj);

        const float4* gA = (const float4*)(inv1 + bi * 800);                 // 200 f4
        const float4* gB = (const float4*)(kn1 + (bj * 32 + h * 16) * 25);   // 100 f4
        for (int e = tid; e < 300; e += 256) {
            if (e < 200) ((float4*)sA)[e] = gA[e];
            else ((float4*)sB)[e - 200] = gB[e - 200];
        }
        __syncthreads();

        int ti = tid >> 4, tj = tid & 15;  // ti: 2 rows each (32), tj: 1 col (16)
        int ibase = bi * 32 + ti * 2;
        int j = bj * 32 + h * 16 + tj;
        float a[2][25];
#pragma unroll
        for (int u = 0; u < 2; ++u)
#pragma unroll
            for (int e = 0; e < 25; ++e) a[u][e] = sA[(ti * 2 + u) * 25 + e];
        float b[25];
#pragma unroll
        for (int e = 0; e < 25; ++e) b[e] = sB[tj * 25 + e];
#pragma unroll
        for (int u = 0; u < 2; ++u) {
            float s = 0.0f;
#pragma unroll
            for (int r = 0; r < 5; ++r)
#pragma unroll
                for (int c = 0; c < 5; ++c) {
                    float m = a[u][r * 5 + 0] * b[c];
#pragma unroll
                    for (int k = 1; k < 5; ++k) m = fmaf(a[u][r * 5 + k], b[k * 5 + c], m);
                    float d = ((r == c) ? 1.0f : 0.0f) - m;
                    s = fmaf(d, d, s);
                }
            bool take = ((ibase + u) > j) && (s < 1.0f);
            contrib += take ? (1.0f - __builtin_amdgcn_sqrtf(s)) : 0.0f;
        }
    }

    // block reduction -> one partial per block, distinct address (no contention)
#pragma unroll
    for (int off = 32; off; off >>= 1) contrib += __shfl_down(contrib, off);
    __shared__ float wsum[4];
    if ((tid & 63) == 0) wsum[tid >> 6] = contrib;
    __syncthreads();
    if (tid == 0) partial[blockIdx.x] = wsum[0] + wsum[1] + wsum[2] + wsum[3];
}

__global__ void finalize_kernel(const float* __restrict__ partial, float* __restrict__ out) {
    int tid = threadIdx.x;
    double s0 = 0.0, s1 = 0.0;
    for (int x = tid; x < NBLK0; x += 256) s0 += (double)partial[x];
    for (int x = NBLK0 + tid; x < NBTOT; x += 256) s1 += (double)partial[x];
#pragma unroll
    for (int off = 32; off; off >>= 1) {
        s0 += __shfl_down(s0, off);
        s1 += __shfl_down(s1, off);
    }
    __shared__ double w0[4], w1[4];
    if ((tid & 63) == 0) { w0[tid >> 6] = s0; w1[tid >> 6] = s1; }
    __syncthreads();
    if (tid == 0) {
        double S0 = w0[0] + w0[1] + w0[2] + w0[3];
        double S1 = w1[0] + w1[1] + w1[2] + w1[3];
        // final = (2*S0/(n0(n0-1)) + 2*S1/(n1(n1-1))) / 2
        double res = S0 / ((double)N0 * (double)(N0 - 1)) +
                     S1 / ((double)N1 * (double)(N1 - 1));
        out[0] = (float)res;
    }
}

extern "C" void kernel_launch(void* const* d_in, const int* in_sizes, int n_in,
                              void* d_out, int out_size, void* d_ws, size_t ws_size,
                              hipStream_t stream) {
    const float* k0 = (const float*)d_in[0];  // (2048,3,3)
    const float* k1 = (const float*)d_in[1];  // (1024,5,5)
    float* out = (float*)d_out;

    float* ws = (float*)d_ws;
    float* kn0 = ws;                  // 18432 floats
    float* inv0 = kn0 + N0 * 9;       // 18432
    float* kn1 = inv0 + N0 * 9;       // 25600
    float* inv1 = kn1 + N1 * 25;      // 25600
    float* partial = inv1 + N1 * 25;  // 2112

    int totalPrep = N0 + N1;  // 3072 threads, block=64 -> 48 blocks
    prep_kernel<<<(totalPrep + 63) / 64, 64, 0, stream>>>(k0, k1, kn0, inv0, kn1, inv1);
    pairs_kernel<<<NBTOT, 256, 0, stream>>>(inv0, kn0, inv1, kn1, partial);
    finalize_kernel<<<1, 256, 0, stream>>>(partial, out);
}